// Round 12
// baseline (56.715 us; speedup 1.0000x reference)
//
#include <hip/hip_runtime.h>
#include <math.h>

// CPMLoss forward on MI355X. Fixed geometry: inputs [8192,4096] f32, P=128, K=16, 4 mods.
// R8/R11 pipeline (best measured: 49.3 us, reproduced twice):
//   1) centers_kernel      : c[m][p][d] = mean_k inputs  (HBM-bound; K=16 hard-coded,
//                            4-way unroll + 4 accumulators for deeper load pipelining)
//   2) pair_partial_kernel : GEMM-style 64x64 tile x 128-D-chunk partial d^2
//   3) red_kernel          : blocks 0..255 rowmin; 256..383 cross-modality diag
//   4) loss_kernel         : weighted relu-mean -> scalar
// Measured dead ends (do not revisit): cooperative grid.sync fusion (170us, R4);
// centers+pair chunk fusion (107us, R5); identity-major centers (60.7us, R6);
// atomic last-block loss tail (+7.6us, R10); nontemporal centers loads (+10us, R9).
#define P_IDS 128
#define D_DIM 4096
#define K_SMP 16
#define MARGIN_F 0.2f
#define NCHUNK 32            // partial-sum chunks (each 128 wide = 2 LDS passes of 64)

// ---------------- 1) centers ----------------
__global__ __launch_bounds__(128) void centers_kernel(const float* __restrict__ in,
                                                      float* __restrict__ c) {
    const int b  = blockIdx.x;            // m*P + p   (512)
    const int ds = blockIdx.y;            // 0..7  (512-float column slab)
    const float* src = in + (size_t)b * K_SMP * D_DIM + ds * 512;
    float* dst = c + (size_t)b * D_DIM + ds * 512;
    const int t = threadIdx.x;            // 0..127 -> one float4 column
    float4 a0 = make_float4(0.f, 0.f, 0.f, 0.f);
    float4 a1 = make_float4(0.f, 0.f, 0.f, 0.f);
    float4 a2 = make_float4(0.f, 0.f, 0.f, 0.f);
    float4 a3 = make_float4(0.f, 0.f, 0.f, 0.f);
    #pragma unroll
    for (int k = 0; k < K_SMP; k += 4) {  // 4 independent loads in flight per step
        float4 v0 = reinterpret_cast<const float4*>(src + (size_t)(k + 0) * D_DIM)[t];
        float4 v1 = reinterpret_cast<const float4*>(src + (size_t)(k + 1) * D_DIM)[t];
        float4 v2 = reinterpret_cast<const float4*>(src + (size_t)(k + 2) * D_DIM)[t];
        float4 v3 = reinterpret_cast<const float4*>(src + (size_t)(k + 3) * D_DIM)[t];
        a0.x += v0.x; a0.y += v0.y; a0.z += v0.z; a0.w += v0.w;
        a1.x += v1.x; a1.y += v1.y; a1.z += v1.z; a1.w += v1.w;
        a2.x += v2.x; a2.y += v2.y; a2.z += v2.z; a2.w += v2.w;
        a3.x += v3.x; a3.y += v3.y; a3.z += v3.z; a3.w += v3.w;
    }
    const float inv = 1.0f / (float)K_SMP;
    float4 r;
    r.x = ((a0.x + a1.x) + (a2.x + a3.x)) * inv;
    r.y = ((a0.y + a1.y) + (a2.y + a3.y)) * inv;
    r.z = ((a0.z + a1.z) + (a2.z + a3.z)) * inv;
    r.w = ((a0.w + a1.w) + (a2.w + a3.w)) * inv;
    reinterpret_cast<float4*>(dst)[t] = r;
}

// ---------------- 2) pairwise partial d^2 (R2-verbatim) ----------------
__global__ __launch_bounds__(256) void pair_partial_kernel(const float* __restrict__ c,
                                                           float* __restrict__ part) {
    __shared__ float As[64][68];
    __shared__ float Bs[64][68];
    const int tid = threadIdx.x;
    const int tx = tid & 15, ty = tid >> 4;
    const int bx = blockIdx.x;            // ((m*2)+it)*2 + jt  (16)
    const int m = bx >> 2, it = (bx >> 1) & 1, jt = bx & 1;
    const int dc = blockIdx.y;            // 0..31, covers D cols [dc*128, dc*128+128)
    const float* cm = c + (size_t)m * P_IDS * D_DIM;
    const float* gA = cm + (size_t)(it * 64) * D_DIM;
    const float* gB = cm + (size_t)(jt * 64) * D_DIM;

    float acc[4][4];
    #pragma unroll
    for (int r = 0; r < 4; ++r)
        #pragma unroll
        for (int s = 0; s < 4; ++s) acc[r][s] = 0.f;

    for (int ch = 0; ch < 2; ++ch) {      // two 64-float sub-chunks
        const int dbase = dc * 128 + ch * 64;
        __syncthreads();
        #pragma unroll
        for (int idx = 0; idx < 4; ++idx) {   // 1024 float4 per tile / 256 thr
            int li = idx * 256 + tid;
            int row = li >> 4, c4 = li & 15;
            float4 va = *reinterpret_cast<const float4*>(gA + (size_t)row * D_DIM + dbase + c4 * 4);
            float4 vb = *reinterpret_cast<const float4*>(gB + (size_t)row * D_DIM + dbase + c4 * 4);
            *reinterpret_cast<float4*>(&As[row][c4 * 4]) = va;
            *reinterpret_cast<float4*>(&Bs[row][c4 * 4]) = vb;
        }
        __syncthreads();
        #pragma unroll
        for (int d4 = 0; d4 < 16; ++d4) {
            float4 a[4], b[4];
            #pragma unroll
            for (int r = 0; r < 4; ++r)
                a[r] = *reinterpret_cast<const float4*>(&As[ty * 4 + r][d4 * 4]);
            #pragma unroll
            for (int s = 0; s < 4; ++s)
                b[s] = *reinterpret_cast<const float4*>(&Bs[s * 16 + tx][d4 * 4]);
            #pragma unroll
            for (int r = 0; r < 4; ++r)
                #pragma unroll
                for (int s = 0; s < 4; ++s) {
                    float dx = a[r].x - b[s].x, dy = a[r].y - b[s].y;
                    float dz = a[r].z - b[s].z, dw = a[r].w - b[s].w;
                    acc[r][s] = fmaf(dx, dx, acc[r][s]);
                    acc[r][s] = fmaf(dy, dy, acc[r][s]);
                    acc[r][s] = fmaf(dz, dz, acc[r][s]);
                    acc[r][s] = fmaf(dw, dw, acc[r][s]);
                }
        }
    }
    float* pbase = part + ((size_t)dc * 4 + m) * P_IDS * P_IDS;
    #pragma unroll
    for (int r = 0; r < 4; ++r) {
        int i = it * 64 + ty * 4 + r;
        #pragma unroll
        for (int s = 0; s < 4; ++s) {
            int j = jt * 64 + s * 16 + tx;
            pbase[i * P_IDS + j] = acc[r][s];
        }
    }
}

// ---------------- 3) merged rowmin (blocks 0..255) + diag (blocks 256..383) ----------------
__global__ __launch_bounds__(256) void red_kernel(const float* __restrict__ part,
                                                  const float* __restrict__ c,
                                                  float* __restrict__ anmin,
                                                  float* __restrict__ diag) {
    const int tid = threadIdx.x;
    const int blk = blockIdx.x;                        // 0..383

    if (blk < 256) {
        // rowmin: rows 2*blk, 2*blk+1 (rowid = m*P + i)
        const int rowid = blk * 2 + (tid >> 7);
        const int j = tid & 127;
        const size_t base = (size_t)rowid * P_IDS + j;
        float sum = 0.f;
        #pragma unroll 4
        for (int dc = 0; dc < NCHUNK; ++dc)
            sum += part[(size_t)dc * 4 * P_IDS * P_IDS + base];
        float d = sqrtf(fmaxf(sum, 1e-12f));
        if (j == (rowid & (P_IDS - 1))) d = INFINITY;
        #pragma unroll
        for (int off = 32; off > 0; off >>= 1) d = fminf(d, __shfl_down(d, off, 64));
        __shared__ float wmin[4];
        if ((tid & 63) == 0) wmin[tid >> 6] = d;
        __syncthreads();
        if (tid == 0) {
            anmin[blk * 2]     = fminf(wmin[0], wmin[1]);
            anmin[blk * 2 + 1] = fminf(wmin[2], wmin[3]);
        }
    } else {
        // diag: identity i = blk-256; wave w -> cross-modality pair:
        // 0:(c2,c3)=ap123  1:(c1,c3)=an123  2:(c1,c4)=ap124  3:(c2,c4)=an124
        const int i = blk - 256;
        const int wave = tid >> 6, lane = tid & 63;
        const int am = (wave == 0 || wave == 3) ? 1 : 0;
        const int bm = (wave <= 1) ? 2 : 3;
        const size_t PD = (size_t)P_IDS * D_DIM;
        const float4* ra = reinterpret_cast<const float4*>(c + am * PD + (size_t)i * D_DIM);
        const float4* rb = reinterpret_cast<const float4*>(c + bm * PD + (size_t)i * D_DIM);
        float acc = 0.f;
        #pragma unroll
        for (int t = 0; t < 16; ++t) {                 // 1024 float4 / 64 lanes
            float4 a = ra[t * 64 + lane];
            float4 b = rb[t * 64 + lane];
            float dx = a.x - b.x, dy = a.y - b.y, dz = a.z - b.z, dw = a.w - b.w;
            acc = fmaf(dx, dx, acc); acc = fmaf(dy, dy, acc);
            acc = fmaf(dz, dz, acc); acc = fmaf(dw, dw, acc);
        }
        #pragma unroll
        for (int off = 32; off > 0; off >>= 1) acc += __shfl_down(acc, off, 64);
        if (lane == 0) diag[wave * P_IDS + i] = sqrtf(fmaxf(acc, 1e-12f));
    }
}

// ---------------- 4) final loss ----------------
__global__ __launch_bounds__(128) void loss_kernel(const float* __restrict__ anmin,
                                                   const float* __restrict__ diag,
                                                   float* __restrict__ out) {
    const int i = threadIdx.x;
    float ap123 = diag[0 * P_IDS + i], an123 = diag[1 * P_IDS + i];
    float ap124 = diag[2 * P_IDS + i], an124 = diag[3 * P_IDS + i];
    float an11 = anmin[0 * P_IDS + i], an22 = anmin[1 * P_IDS + i];
    float an33 = anmin[2 * P_IDS + i], an44 = anmin[3 * P_IDS + i];
    float s = fmaxf(ap123 - an123 + MARGIN_F, 0.f)
            + 0.5f * (fmaxf(ap123 - an33 + MARGIN_F, 0.f) +
                      fmaxf(ap123 - an11 + MARGIN_F, 0.f))
            + fmaxf(ap124 - an124 + MARGIN_F, 0.f)
            + 0.5f * (fmaxf(ap124 - an44 + MARGIN_F, 0.f) +
                      fmaxf(ap124 - an22 + MARGIN_F, 0.f));
    #pragma unroll
    for (int off = 32; off > 0; off >>= 1) s += __shfl_down(s, off, 64);
    __shared__ float w[2];
    if ((threadIdx.x & 63) == 0) w[threadIdx.x >> 6] = s;
    __syncthreads();
    if (threadIdx.x == 0) out[0] = (w[0] + w[1]) / (2.0f * (float)P_IDS);
}

extern "C" void kernel_launch(void* const* d_in, const int* in_sizes, int n_in,
                              void* d_out, int out_size, void* d_ws, size_t ws_size,
                              hipStream_t stream) {
    const float* in = (const float*)d_in[0];

    float* c     = (float*)d_ws;                              // 4*128*4096 f32 = 8 MiB
    float* part  = c + (size_t)4 * P_IDS * D_DIM;             // 32*4*16384 f32 = 8.4 MB
    float* anmin = part + (size_t)NCHUNK * 4 * P_IDS * P_IDS; // 512 f32
    float* diag  = anmin + 4 * P_IDS;                         // 512 f32

    hipLaunchKernelGGL(centers_kernel, dim3(4 * P_IDS, 8), dim3(128), 0, stream, in, c);
    hipLaunchKernelGGL(pair_partial_kernel, dim3(16, NCHUNK), dim3(256), 0, stream, c, part);
    hipLaunchKernelGGL(red_kernel, dim3(384), dim3(256), 0, stream, part, c, anmin, diag);
    hipLaunchKernelGGL(loss_kernel, dim3(1), dim3(128), 0, stream, anmin, diag, (float*)d_out);
}

// Round 13
// 49.220 us; speedup vs baseline: 1.1523x; 1.1523x over previous
//
#include <hip/hip_runtime.h>
#include <math.h>

// CPMLoss forward on MI355X. Fixed geometry: inputs [8192,4096] f32, P=128, K=16, 4 mods.
// R8/R11-exact pipeline (best measured: 49.32/49.36 us, reproduced):
//   1) centers_kernel      : c[m][p][d] = mean_k inputs  (HBM-bound; ROLLED k-loop —
//                            keeps each wave's requests page-clustered; unroll = +7.4us)
//   2) pair_partial_kernel : GEMM-style 64x64 tile x 128-D-chunk partial d^2
//   3) red_kernel          : blocks 0..255 rowmin; 256..383 cross-modality diag
//   4) loss_kernel         : weighted relu-mean -> scalar
// Measured dead ends (do not revisit): cooperative grid.sync fusion (170us, R4);
// centers+pair chunk fusion (107us, R5); identity-major centers (60.7us, R6);
// atomic last-block loss tail (+7.6us, R10); nontemporal centers loads (+10us, R9);
// 4-way unrolled centers (+7.4us, R12).
#define P_IDS 128
#define D_DIM 4096
#define MARGIN_F 0.2f
#define NCHUNK 32            // partial-sum chunks (each 128 wide = 2 LDS passes of 64)

// ---------------- 1) centers ----------------
__global__ __launch_bounds__(128) void centers_kernel(const float* __restrict__ in,
                                                      float* __restrict__ c, int K) {
    const int b  = blockIdx.x;            // m*P + p   (512)
    const int ds = blockIdx.y;            // 0..7  (512-float column slab)
    const float* src = in + (size_t)b * K * D_DIM + ds * 512;
    float* dst = c + (size_t)b * D_DIM + ds * 512;
    const float inv = 1.0f / (float)K;
    float4 acc = make_float4(0.f, 0.f, 0.f, 0.f);
    const int t = threadIdx.x;            // 0..127 -> one float4 column
    for (int k = 0; k < K; ++k) {
        float4 v = reinterpret_cast<const float4*>(src + (size_t)k * D_DIM)[t];
        acc.x += v.x; acc.y += v.y; acc.z += v.z; acc.w += v.w;
    }
    acc.x *= inv; acc.y *= inv; acc.z *= inv; acc.w *= inv;
    reinterpret_cast<float4*>(dst)[t] = acc;
}

// ---------------- 2) pairwise partial d^2 ----------------
__global__ __launch_bounds__(256) void pair_partial_kernel(const float* __restrict__ c,
                                                           float* __restrict__ part) {
    __shared__ float As[64][68];
    __shared__ float Bs[64][68];
    const int tid = threadIdx.x;
    const int tx = tid & 15, ty = tid >> 4;
    const int bx = blockIdx.x;            // ((m*2)+it)*2 + jt  (16)
    const int m = bx >> 2, it = (bx >> 1) & 1, jt = bx & 1;
    const int dc = blockIdx.y;            // 0..31, covers D cols [dc*128, dc*128+128)
    const float* cm = c + (size_t)m * P_IDS * D_DIM;
    const float* gA = cm + (size_t)(it * 64) * D_DIM;
    const float* gB = cm + (size_t)(jt * 64) * D_DIM;

    float acc[4][4];
    #pragma unroll
    for (int r = 0; r < 4; ++r)
        #pragma unroll
        for (int s = 0; s < 4; ++s) acc[r][s] = 0.f;

    for (int ch = 0; ch < 2; ++ch) {      // two 64-float sub-chunks
        const int dbase = dc * 128 + ch * 64;
        __syncthreads();
        #pragma unroll
        for (int idx = 0; idx < 4; ++idx) {   // 1024 float4 per tile / 256 thr
            int li = idx * 256 + tid;
            int row = li >> 4, c4 = li & 15;
            float4 va = *reinterpret_cast<const float4*>(gA + (size_t)row * D_DIM + dbase + c4 * 4);
            float4 vb = *reinterpret_cast<const float4*>(gB + (size_t)row * D_DIM + dbase + c4 * 4);
            *reinterpret_cast<float4*>(&As[row][c4 * 4]) = va;
            *reinterpret_cast<float4*>(&Bs[row][c4 * 4]) = vb;
        }
        __syncthreads();
        #pragma unroll
        for (int d4 = 0; d4 < 16; ++d4) {
            float4 a[4], b[4];
            #pragma unroll
            for (int r = 0; r < 4; ++r)
                a[r] = *reinterpret_cast<const float4*>(&As[ty * 4 + r][d4 * 4]);
            #pragma unroll
            for (int s = 0; s < 4; ++s)
                b[s] = *reinterpret_cast<const float4*>(&Bs[s * 16 + tx][d4 * 4]);
            #pragma unroll
            for (int r = 0; r < 4; ++r)
                #pragma unroll
                for (int s = 0; s < 4; ++s) {
                    float dx = a[r].x - b[s].x, dy = a[r].y - b[s].y;
                    float dz = a[r].z - b[s].z, dw = a[r].w - b[s].w;
                    acc[r][s] = fmaf(dx, dx, acc[r][s]);
                    acc[r][s] = fmaf(dy, dy, acc[r][s]);
                    acc[r][s] = fmaf(dz, dz, acc[r][s]);
                    acc[r][s] = fmaf(dw, dw, acc[r][s]);
                }
        }
    }
    float* pbase = part + ((size_t)dc * 4 + m) * P_IDS * P_IDS;
    #pragma unroll
    for (int r = 0; r < 4; ++r) {
        int i = it * 64 + ty * 4 + r;
        #pragma unroll
        for (int s = 0; s < 4; ++s) {
            int j = jt * 64 + s * 16 + tx;
            pbase[i * P_IDS + j] = acc[r][s];
        }
    }
}

// ---------------- 3) merged rowmin (blocks 0..255) + diag (blocks 256..383) ----------------
__global__ __launch_bounds__(256) void red_kernel(const float* __restrict__ part,
                                                  const float* __restrict__ c,
                                                  float* __restrict__ anmin,
                                                  float* __restrict__ diag) {
    const int tid = threadIdx.x;
    const int blk = blockIdx.x;                        // 0..383

    if (blk < 256) {
        // rowmin: rows 2*blk, 2*blk+1 (rowid = m*P + i)
        const int rowid = blk * 2 + (tid >> 7);
        const int j = tid & 127;
        const size_t base = (size_t)rowid * P_IDS + j;
        float sum = 0.f;
        #pragma unroll 4
        for (int dc = 0; dc < NCHUNK; ++dc)
            sum += part[(size_t)dc * 4 * P_IDS * P_IDS + base];
        float d = sqrtf(fmaxf(sum, 1e-12f));
        if (j == (rowid & (P_IDS - 1))) d = INFINITY;
        #pragma unroll
        for (int off = 32; off > 0; off >>= 1) d = fminf(d, __shfl_down(d, off, 64));
        __shared__ float wmin[4];
        if ((tid & 63) == 0) wmin[tid >> 6] = d;
        __syncthreads();
        if (tid == 0) {
            anmin[blk * 2]     = fminf(wmin[0], wmin[1]);
            anmin[blk * 2 + 1] = fminf(wmin[2], wmin[3]);
        }
    } else {
        // diag: identity i = blk-256; wave w -> cross-modality pair:
        // 0:(c2,c3)=ap123  1:(c1,c3)=an123  2:(c1,c4)=ap124  3:(c2,c4)=an124
        const int i = blk - 256;
        const int wave = tid >> 6, lane = tid & 63;
        const int am = (wave == 0 || wave == 3) ? 1 : 0;
        const int bm = (wave <= 1) ? 2 : 3;
        const size_t PD = (size_t)P_IDS * D_DIM;
        const float4* ra = reinterpret_cast<const float4*>(c + am * PD + (size_t)i * D_DIM);
        const float4* rb = reinterpret_cast<const float4*>(c + bm * PD + (size_t)i * D_DIM);
        float acc = 0.f;
        #pragma unroll
        for (int t = 0; t < 16; ++t) {                 // 1024 float4 / 64 lanes
            float4 a = ra[t * 64 + lane];
            float4 b = rb[t * 64 + lane];
            float dx = a.x - b.x, dy = a.y - b.y, dz = a.z - b.z, dw = a.w - b.w;
            acc = fmaf(dx, dx, acc); acc = fmaf(dy, dy, acc);
            acc = fmaf(dz, dz, acc); acc = fmaf(dw, dw, acc);
        }
        #pragma unroll
        for (int off = 32; off > 0; off >>= 1) acc += __shfl_down(acc, off, 64);
        if (lane == 0) diag[wave * P_IDS + i] = sqrtf(fmaxf(acc, 1e-12f));
    }
}

// ---------------- 4) final loss ----------------
__global__ __launch_bounds__(128) void loss_kernel(const float* __restrict__ anmin,
                                                   const float* __restrict__ diag,
                                                   float* __restrict__ out) {
    const int i = threadIdx.x;
    float ap123 = diag[0 * P_IDS + i], an123 = diag[1 * P_IDS + i];
    float ap124 = diag[2 * P_IDS + i], an124 = diag[3 * P_IDS + i];
    float an11 = anmin[0 * P_IDS + i], an22 = anmin[1 * P_IDS + i];
    float an33 = anmin[2 * P_IDS + i], an44 = anmin[3 * P_IDS + i];
    float s = fmaxf(ap123 - an123 + MARGIN_F, 0.f)
            + 0.5f * (fmaxf(ap123 - an33 + MARGIN_F, 0.f) +
                      fmaxf(ap123 - an11 + MARGIN_F, 0.f))
            + fmaxf(ap124 - an124 + MARGIN_F, 0.f)
            + 0.5f * (fmaxf(ap124 - an44 + MARGIN_F, 0.f) +
                      fmaxf(ap124 - an22 + MARGIN_F, 0.f));
    #pragma unroll
    for (int off = 32; off > 0; off >>= 1) s += __shfl_down(s, off, 64);
    __shared__ float w[2];
    if ((threadIdx.x & 63) == 0) w[threadIdx.x >> 6] = s;
    __syncthreads();
    if (threadIdx.x == 0) out[0] = (w[0] + w[1]) / (2.0f * (float)P_IDS);
}

extern "C" void kernel_launch(void* const* d_in, const int* in_sizes, int n_in,
                              void* d_out, int out_size, void* d_ws, size_t ws_size,
                              hipStream_t stream) {
    const float* in = (const float*)d_in[0];
    const int N = in_sizes[1];            // 8192
    const int K = N / (4 * P_IDS);        // 16

    float* c     = (float*)d_ws;                              // 4*128*4096 f32 = 8 MiB
    float* part  = c + (size_t)4 * P_IDS * D_DIM;             // 32*4*16384 f32 = 8.4 MB
    float* anmin = part + (size_t)NCHUNK * 4 * P_IDS * P_IDS; // 512 f32
    float* diag  = anmin + 4 * P_IDS;                         // 512 f32

    hipLaunchKernelGGL(centers_kernel, dim3(4 * P_IDS, 8), dim3(128), 0, stream, in, c, K);
    hipLaunchKernelGGL(pair_partial_kernel, dim3(16, NCHUNK), dim3(256), 0, stream, c, part);
    hipLaunchKernelGGL(red_kernel, dim3(384), dim3(256), 0, stream, part, c, anmin, diag);
    hipLaunchKernelGGL(loss_kernel, dim3(1), dim3(128), 0, stream, anmin, diag, (float*)d_out);
}